// Round 1
// baseline (1130.927 us; speedup 1.0000x reference)
//
#include <hip/hip_runtime.h>

#define BATCH 64
#define TT    1024
#define INC   16
#define NN    512
#define RNK   16
#define OUTC  8

// a = DT/TAU = 0.1
#define A_COEF 0.1f

__device__ __forceinline__ float fast_tanh(float x) {
    // tanh(x) = 1 - 2/(exp(2x)+1); safe at +/-inf
    float e = __expf(2.0f * x);
    return 1.0f - __fdividef(2.0f, e + 1.0f);
}

// Barrier with LDS ordering only (does NOT drain vmcnt: h stores are
// fire-and-forget, never read in-kernel).
__device__ __forceinline__ void lgkm_barrier() {
    asm volatile("s_waitcnt lgkmcnt(0)\n\ts_barrier" ::: "memory");
}

// ---- DPP cross-lane adds (VALU pipe, ~4-8 cyc/stage vs ~100 for ds_bpermute) ----
// dpp_ctrl: row_shr:N = 0x110+N, row_bcast15 = 0x142, row_bcast31 = 0x143
template<int CTRL>
__device__ __forceinline__ float dpp_add(float x) {
    int y = __builtin_amdgcn_update_dpp(0, __float_as_int(x), CTRL, 0xF, 0xF, true);
    return x + __int_as_float(y);
}

// Sum over each 32-lane half-wave; result valid in lanes 31 and 63.
__device__ __forceinline__ float half_wave_sum(float x) {
    x = dpp_add<0x111>(x);  // row_shr:1
    x = dpp_add<0x112>(x);  // row_shr:2
    x = dpp_add<0x114>(x);  // row_shr:4
    x = dpp_add<0x118>(x);  // row_shr:8  -> row sums at lanes 15/31/47/63
    x = dpp_add<0x142>(x);  // row_bcast15 -> 32-group sums at lanes 31/63
    return x;
}

// Full 64-lane sum; result valid in lane 63.
__device__ __forceinline__ float wave_sum(float x) {
    x = half_wave_sum(x);
    x = dpp_add<0x143>(x);  // row_bcast31 -> total at lane 63
    return x;
}

// ---------------------------------------------------------------------------
// Scan kernel: 2 batches per 1024-thread block (32 blocks), so each CU hosts
// 16 waves = 4 waves/SIMD (vs 2 before) to hide the serial-scan latency.
// Per 512-thread half: one lane per state n. Weights in registers; phi and
// low round-trip LDS with lgkm-only barriers; reduces via DPP.
// x is read directly from global (wave-uniform 64B/step, L1/L2 broadcast),
// prefetched one iteration ahead. Out-projection moved to a post-kernel.
// ---------------------------------------------------------------------------
__global__ __launch_bounds__(1024) void scan_kernel(
    const float* __restrict__ x,      // [B,T,INC]
    const float* __restrict__ In_w,   // [N,INC]
    const float* __restrict__ V_w,    // [R,N]
    const float* __restrict__ U_w,    // [N,R]
    const float* __restrict__ h0,     // [N]
    float* __restrict__ hidden)       // [B,T,N]
{
    const int half = threadIdx.x >> 9;   // which batch of the pair
    const int tid  = threadIdx.x & 511;  // lane within the batch (state n)
    const int b    = (blockIdx.x << 1) | half;
    const int rr   = tid >> 5;           // low-rank reduce: which r this lane serves
    const int g    = tid & 31;           // position within the 32-lane reduce group

    __shared__ __align__(16) float phi_s[2][NN];
    __shared__ __align__(16) float low_s[2][RNK];

    // ---- per-lane weights in registers ----
    float Ur[RNK];
    #pragma unroll
    for (int r = 0; r < RNK; ++r) Ur[r] = U_w[tid * RNK + r];

    float Wr[INC];
    #pragma unroll
    for (int i = 0; i < INC; ++i) Wr[i] = In_w[tid * INC + i];

    // V fragment: lane (rr,g) covers n' = k*128 + g*4 + j
    float Vr[16];
    #pragma unroll
    for (int k = 0; k < 4; ++k)
        #pragma unroll
        for (int j = 0; j < 4; ++j)
            Vr[k * 4 + j] = V_w[rr * NN + k * 128 + g * 4 + j];

    float h = h0[tid];

    const float* xb = x + (size_t)b * TT * INC;
    float* hb = hidden + (size_t)b * TT * NN;

    // x for t=0 (wave-uniform broadcast loads)
    float4 xv0, xv1, xv2, xv3;
    {
        const float4* xp = (const float4*)xb;
        xv0 = xp[0]; xv1 = xp[1]; xv2 = xp[2]; xv3 = xp[3];
    }

    for (int t = 0; t < TT; ++t) {
        float phi = fast_tanh(h);
        phi_s[half][tid] = phi;

        // input projection with current x (independent of phi chain, 4-acc tree)
        float ia = Wr[0] * xv0.x;
        float ib = Wr[1] * xv0.y;
        float ic = Wr[2] * xv0.z;
        float id = Wr[3] * xv0.w;
        ia = fmaf(Wr[4],  xv1.x, ia);
        ib = fmaf(Wr[5],  xv1.y, ib);
        ic = fmaf(Wr[6],  xv1.z, ic);
        id = fmaf(Wr[7],  xv1.w, id);
        ia = fmaf(Wr[8],  xv2.x, ia);
        ib = fmaf(Wr[9],  xv2.y, ib);
        ic = fmaf(Wr[10], xv2.z, ic);
        id = fmaf(Wr[11], xv2.w, id);
        ia = fmaf(Wr[12], xv3.x, ia);
        ib = fmaf(Wr[13], xv3.y, ib);
        ic = fmaf(Wr[14], xv3.z, ic);
        id = fmaf(Wr[15], xv3.w, id);
        float inp = (ia + ib) + (ic + id);

        lgkm_barrier();   // phi visible

        // ---- low[rr] partial over this lane's 16 n's (4-acc tree) ----
        float p0 = 0.f, p1 = 0.f, p2 = 0.f, p3 = 0.f;
        #pragma unroll
        for (int k = 0; k < 4; ++k) {
            float4 ph = *(const float4*)&phi_s[half][k * 128 + g * 4];
            p0 = fmaf(Vr[k * 4 + 0], ph.x, p0);
            p1 = fmaf(Vr[k * 4 + 1], ph.y, p1);
            p2 = fmaf(Vr[k * 4 + 2], ph.z, p2);
            p3 = fmaf(Vr[k * 4 + 3], ph.w, p3);
        }
        float partial = (p0 + p1) + (p2 + p3);
        partial = half_wave_sum(partial);          // DPP
        if (g == 31) low_s[half][rr] = partial;    // lanes 31/63 of each wave

        // prefetch x for t+1 (vector broadcast load; vmcnt drained only at use)
        {
            int tn = (t + 1 < TT) ? t + 1 : t;
            const float4* xp = (const float4*)(xb + tn * INC);
            xv0 = xp[0]; xv1 = xp[1]; xv2 = xp[2]; xv3 = xp[3];
        }

        lgkm_barrier();   // low visible

        // ---- rec = U[n,:] . low (4-acc tree) ----
        float4 l0 = *(const float4*)&low_s[half][0];
        float4 l1 = *(const float4*)&low_s[half][4];
        float4 l2 = *(const float4*)&low_s[half][8];
        float4 l3 = *(const float4*)&low_s[half][12];
        float ra = Ur[0] * l0.x;
        float rb = Ur[1] * l0.y;
        float rc = Ur[2] * l0.z;
        float rd = Ur[3] * l0.w;
        ra = fmaf(Ur[4],  l1.x, ra);
        rb = fmaf(Ur[5],  l1.y, rb);
        rc = fmaf(Ur[6],  l1.z, rc);
        rd = fmaf(Ur[7],  l1.w, rd);
        ra = fmaf(Ur[8],  l2.x, ra);
        rb = fmaf(Ur[9],  l2.y, rb);
        rc = fmaf(Ur[10], l2.z, rc);
        rd = fmaf(Ur[11], l2.w, rd);
        ra = fmaf(Ur[12], l3.x, ra);
        rb = fmaf(Ur[13], l3.y, rb);
        rc = fmaf(Ur[14], l3.z, rc);
        rd = fmaf(Ur[15], l3.w, rd);
        float rec = (ra + rb) + (rc + rd);

        h = fmaf(A_COEF, (rec + inp) - h, h);   // (1-a)h + a(rec+inp)
        hb[t * NN + tid] = h;                   // fire-and-forget (never drained)
    }
}

// ---------------------------------------------------------------------------
// Out-projection post-pass: out[b,t,o] = sum_n Out_w[o,n] * tanh(hidden[b,t,n])
// One wave per (b,t) row, grid-stride. Memory-bound (~128 MB read, largely
// L3-resident); runs on all 256 CUs in parallel, off the scan's critical path.
// ---------------------------------------------------------------------------
__global__ __launch_bounds__(256) void out_kernel(
    const float* __restrict__ hidden,  // [B,T,N]
    const float* __restrict__ Out_w,   // [OUTC,N]
    float* __restrict__ out)           // [B,T,OUTC]
{
    const int wv = (blockIdx.x << 2) | (threadIdx.x >> 6);  // global wave id
    const int p  = threadIdx.x & 63;                        // lane in wave
    const int NW = gridDim.x << 2;

    // Ow regs: lane p covers n in {p*4..p*4+3} and {256+p*4..256+p*4+3}
    float Ow[OUTC][8];
    #pragma unroll
    for (int o = 0; o < OUTC; ++o) {
        float4 w0 = *(const float4*)&Out_w[o * NN + p * 4];
        float4 w1 = *(const float4*)&Out_w[o * NN + 256 + p * 4];
        Ow[o][0] = w0.x; Ow[o][1] = w0.y; Ow[o][2] = w0.z; Ow[o][3] = w0.w;
        Ow[o][4] = w1.x; Ow[o][5] = w1.y; Ow[o][6] = w1.z; Ow[o][7] = w1.w;
    }

    const int ROWS = BATCH * TT;
    for (int r = wv; r < ROWS; r += NW) {
        const float4* hp = (const float4*)(hidden + (size_t)r * NN);
        float4 a = hp[p];        // n = p*4 .. p*4+3       (coalesced 1 KB/wave)
        float4 c = hp[64 + p];   // n = 256+p*4 .. +3      (coalesced 1 KB/wave)
        float ph[8];
        ph[0] = fast_tanh(a.x); ph[1] = fast_tanh(a.y);
        ph[2] = fast_tanh(a.z); ph[3] = fast_tanh(a.w);
        ph[4] = fast_tanh(c.x); ph[5] = fast_tanh(c.y);
        ph[6] = fast_tanh(c.z); ph[7] = fast_tanh(c.w);
        #pragma unroll
        for (int o = 0; o < OUTC; ++o) {
            float sa = Ow[o][0] * ph[0];
            float sb = Ow[o][1] * ph[1];
            sa = fmaf(Ow[o][2], ph[2], sa);
            sb = fmaf(Ow[o][3], ph[3], sb);
            sa = fmaf(Ow[o][4], ph[4], sa);
            sb = fmaf(Ow[o][5], ph[5], sb);
            sa = fmaf(Ow[o][6], ph[6], sa);
            sb = fmaf(Ow[o][7], ph[7], sb);
            float s = sa + sb;
            s = wave_sum(s);                      // DPP, result in lane 63
            if (p == 63) out[(size_t)r * OUTC + o] = s;
        }
    }
}

extern "C" void kernel_launch(void* const* d_in, const int* in_sizes, int n_in,
                              void* d_out, int out_size, void* d_ws, size_t ws_size,
                              hipStream_t stream) {
    const float* x    = (const float*)d_in[0];  // [64,1024,16]
    const float* In_w = (const float*)d_in[1];  // [512,16]
    const float* V_w  = (const float*)d_in[2];  // [16,512]
    const float* U_w  = (const float*)d_in[3];  // [512,16]
    const float* Ow   = (const float*)d_in[4];  // [8,512]
    const float* h0   = (const float*)d_in[5];  // [512]

    float* hidden = (float*)d_out;                         // [64,1024,512]
    float* out    = hidden + (size_t)BATCH * TT * NN;      // [64,1024,8]

    // 32 blocks x 1024 threads: 2 batches per block -> 4 waves/SIMD on 32 CUs.
    scan_kernel<<<BATCH / 2, 1024, 0, stream>>>(x, In_w, V_w, U_w, h0, hidden);
    // Out-projection from stored hidden: 1024 blocks x 256 thr = 4096 waves.
    out_kernel<<<1024, 256, 0, stream>>>(hidden, Ow, out);
}

// Round 2
// 741.752 us; speedup vs baseline: 1.5247x; 1.5247x over previous
//
#include <hip/hip_runtime.h>

#define BATCH 64
#define TT    1024
#define INC   16
#define NN    512
#define RNK   16
#define OUTC  8

// a = DT/TAU = 0.1
#define A_COEF 0.1f

__device__ __forceinline__ float fast_tanh(float x) {
    // tanh(x) = 1 - 2/(exp(2x)+1); safe at +/-inf
    float e = __expf(2.0f * x);
    return 1.0f - __fdividef(2.0f, e + 1.0f);
}

// Barrier with LDS ordering only (does NOT drain vmcnt: h stores are
// fire-and-forget, never read in-kernel).
__device__ __forceinline__ void lgkm_barrier() {
    asm volatile("s_waitcnt lgkmcnt(0)\n\ts_barrier" ::: "memory");
}

// ---- DPP cross-lane adds (VALU pipe) ----
// dpp_ctrl: row_shr:N = 0x110+N, row_bcast15 = 0x142, row_bcast31 = 0x143
template<int CTRL>
__device__ __forceinline__ float dpp_add(float x) {
    int y = __builtin_amdgcn_update_dpp(0, __float_as_int(x), CTRL, 0xF, 0xF, true);
    return x + __int_as_float(y);
}

// Sum over each 32-lane half-wave; result valid in lanes 31 and 63.
__device__ __forceinline__ float half_wave_sum(float x) {
    x = dpp_add<0x111>(x);  // row_shr:1
    x = dpp_add<0x112>(x);  // row_shr:2
    x = dpp_add<0x114>(x);  // row_shr:4
    x = dpp_add<0x118>(x);  // row_shr:8  -> row sums at lanes 15/31/47/63
    x = dpp_add<0x142>(x);  // row_bcast15 -> 32-group sums at lanes 31/63
    return x;
}

// Full 64-lane sum; result valid in lane 63.
__device__ __forceinline__ float wave_sum(float x) {
    x = half_wave_sum(x);
    x = dpp_add<0x143>(x);  // row_bcast31 -> total at lane 63
    return x;
}

// ---------------------------------------------------------------------------
// Scan kernel: one batch per block, 256 threads (4 waves), 2 states per lane.
// Rationale vs the 512-thread version:
//  - barrier arrival/resume spread halves (4 waves sync, not 8)
//  - each 32-lane group computes TWO r's (rr, rr+8) from the same phi loads:
//    phi read-multiplicity 16 -> 8 (V-gather LDS traffic halved, same
//    bank-clean stride-16B pattern)
//  - out-projection removed from the loop (it owned all LDS bank conflicts:
//    stride-32B phi reads) -> separate memory-bound out_kernel
// Weights in registers; x staged in LDS once (zero vmcnt waits in the loop);
// phi/low round-trip LDS with lgkm-only barriers; reduces via DPP.
// ---------------------------------------------------------------------------
__global__ __launch_bounds__(256, 1) void scan_kernel(
    const float* __restrict__ x,      // [B,T,INC]
    const float* __restrict__ In_w,   // [N,INC]
    const float* __restrict__ V_w,    // [R,N]
    const float* __restrict__ U_w,    // [N,R]
    const float* __restrict__ h0,     // [N]
    float* __restrict__ hidden)       // [B,T,N]
{
    const int b  = blockIdx.x;
    const int p  = threadIdx.x;     // 0..255; owns states n0=2p, n1=2p+1
    const int rr = p >> 5;          // reduce group 0..7 -> computes r=rr, r=rr+8
    const int g  = p & 31;          // position within the 32-lane reduce group
    const int n0 = p << 1;

    __shared__ __align__(16) float xs[TT * INC];  // 64 KB: whole x[b]
    __shared__ __align__(16) float phi_s[NN];
    __shared__ __align__(16) float low_s[RNK];

    // ---- stage x[b] (64 KB) into LDS, coalesced float4 ----
    {
        const float4* src = (const float4*)(x + (size_t)b * TT * INC);
        float4* dst = (float4*)xs;
        #pragma unroll
        for (int c = 0; c < 16; ++c)
            dst[c * 256 + p] = src[c * 256 + p];
    }

    // ---- per-lane weights in registers ----
    float Ur[2][RNK];   // U rows n0, n1
    #pragma unroll
    for (int r = 0; r < RNK; ++r) {
        Ur[0][r] = U_w[n0 * RNK + r];
        Ur[1][r] = U_w[(n0 + 1) * RNK + r];
    }

    float Wr[2][INC];   // In_w rows n0, n1
    #pragma unroll
    for (int i = 0; i < INC; ++i) {
        Wr[0][i] = In_w[n0 * INC + i];
        Wr[1][i] = In_w[(n0 + 1) * INC + i];
    }

    // V fragments: group (rr,g) covers n' = k*128 + g*4 + j for r=rr and r=rr+8
    float Vr[2][16];
    #pragma unroll
    for (int k = 0; k < 4; ++k)
        #pragma unroll
        for (int j = 0; j < 4; ++j) {
            Vr[0][k * 4 + j] = V_w[rr * NN + k * 128 + g * 4 + j];
            Vr[1][k * 4 + j] = V_w[(rr + 8) * NN + k * 128 + g * 4 + j];
        }

    float2 h = *(const float2*)&h0[n0];

    __syncthreads();  // full drain once: staging + weight loads visible

    float* hb = hidden + (size_t)b * TT * NN;

    // x for t=0 (uniform-address broadcast reads from LDS)
    float4 xv0, xv1, xv2, xv3;
    {
        const float4* xp = (const float4*)xs;
        xv0 = xp[0]; xv1 = xp[1]; xv2 = xp[2]; xv3 = xp[3];
    }

    for (int t = 0; t < TT; ++t) {
        float phi0 = fast_tanh(h.x);
        float phi1 = fast_tanh(h.y);
        ((float2*)phi_s)[p] = make_float2(phi0, phi1);  // b64, 2-way banks (free)

        // input projection for both states (independent of phi chain)
        float ia0 = Wr[0][0] * xv0.x, ib0 = Wr[0][1] * xv0.y;
        float ic0 = Wr[0][2] * xv0.z, id0 = Wr[0][3] * xv0.w;
        float ia1 = Wr[1][0] * xv0.x, ib1 = Wr[1][1] * xv0.y;
        float ic1 = Wr[1][2] * xv0.z, id1 = Wr[1][3] * xv0.w;
        ia0 = fmaf(Wr[0][4],  xv1.x, ia0); ib0 = fmaf(Wr[0][5],  xv1.y, ib0);
        ic0 = fmaf(Wr[0][6],  xv1.z, ic0); id0 = fmaf(Wr[0][7],  xv1.w, id0);
        ia1 = fmaf(Wr[1][4],  xv1.x, ia1); ib1 = fmaf(Wr[1][5],  xv1.y, ib1);
        ic1 = fmaf(Wr[1][6],  xv1.z, ic1); id1 = fmaf(Wr[1][7],  xv1.w, id1);
        ia0 = fmaf(Wr[0][8],  xv2.x, ia0); ib0 = fmaf(Wr[0][9],  xv2.y, ib0);
        ic0 = fmaf(Wr[0][10], xv2.z, ic0); id0 = fmaf(Wr[0][11], xv2.w, id0);
        ia1 = fmaf(Wr[1][8],  xv2.x, ia1); ib1 = fmaf(Wr[1][9],  xv2.y, ib1);
        ic1 = fmaf(Wr[1][10], xv2.z, ic1); id1 = fmaf(Wr[1][11], xv2.w, id1);
        ia0 = fmaf(Wr[0][12], xv3.x, ia0); ib0 = fmaf(Wr[0][13], xv3.y, ib0);
        ic0 = fmaf(Wr[0][14], xv3.z, ic0); id0 = fmaf(Wr[0][15], xv3.w, id0);
        ia1 = fmaf(Wr[1][12], xv3.x, ia1); ib1 = fmaf(Wr[1][13], xv3.y, ib1);
        ic1 = fmaf(Wr[1][14], xv3.z, ic1); id1 = fmaf(Wr[1][15], xv3.w, id1);
        float inp0 = (ia0 + ib0) + (ic0 + id0);
        float inp1 = (ia1 + ib1) + (ic1 + id1);

        lgkm_barrier();   // phi visible

        // ---- low partials for r=rr and r=rr+8 over this lane's 16 n's ----
        float a0 = 0.f, a1 = 0.f, a2 = 0.f, a3 = 0.f;   // chain for rr
        float b0 = 0.f, b1 = 0.f, b2 = 0.f, b3 = 0.f;   // chain for rr+8
        #pragma unroll
        for (int k = 0; k < 4; ++k) {
            float4 ph = *(const float4*)&phi_s[k * 128 + g * 4];  // stride 16B: bank-clean
            a0 = fmaf(Vr[0][k * 4 + 0], ph.x, a0);
            a1 = fmaf(Vr[0][k * 4 + 1], ph.y, a1);
            a2 = fmaf(Vr[0][k * 4 + 2], ph.z, a2);
            a3 = fmaf(Vr[0][k * 4 + 3], ph.w, a3);
            b0 = fmaf(Vr[1][k * 4 + 0], ph.x, b0);
            b1 = fmaf(Vr[1][k * 4 + 1], ph.y, b1);
            b2 = fmaf(Vr[1][k * 4 + 2], ph.z, b2);
            b3 = fmaf(Vr[1][k * 4 + 3], ph.w, b3);
        }
        float pA = (a0 + a1) + (a2 + a3);
        float pB = (b0 + b1) + (b2 + b3);
        pA = half_wave_sum(pA);            // two independent DPP chains, pipelined
        pB = half_wave_sum(pB);
        if (g == 31) {
            low_s[rr]     = pA;
            low_s[rr + 8] = pB;
        }

        // prefetch x for t+1 (uniform LDS reads; drains at barrier2)
        {
            int tn = (t + 1 < TT) ? t + 1 : t;
            const float4* xp = (const float4*)(xs + tn * INC);
            xv0 = xp[0]; xv1 = xp[1]; xv2 = xp[2]; xv3 = xp[3];
        }

        lgkm_barrier();   // low visible

        // ---- rec = U[n,:] . low for both states (broadcast low reads) ----
        float4 l0 = *(const float4*)&low_s[0];
        float4 l1 = *(const float4*)&low_s[4];
        float4 l2 = *(const float4*)&low_s[8];
        float4 l3 = *(const float4*)&low_s[12];
        float r0a = Ur[0][0] * l0.x, r0b = Ur[0][1] * l0.y;
        float r0c = Ur[0][2] * l0.z, r0d = Ur[0][3] * l0.w;
        float r1a = Ur[1][0] * l0.x, r1b = Ur[1][1] * l0.y;
        float r1c = Ur[1][2] * l0.z, r1d = Ur[1][3] * l0.w;
        r0a = fmaf(Ur[0][4],  l1.x, r0a); r0b = fmaf(Ur[0][5],  l1.y, r0b);
        r0c = fmaf(Ur[0][6],  l1.z, r0c); r0d = fmaf(Ur[0][7],  l1.w, r0d);
        r1a = fmaf(Ur[1][4],  l1.x, r1a); r1b = fmaf(Ur[1][5],  l1.y, r1b);
        r1c = fmaf(Ur[1][6],  l1.z, r1c); r1d = fmaf(Ur[1][7],  l1.w, r1d);
        r0a = fmaf(Ur[0][8],  l2.x, r0a); r0b = fmaf(Ur[0][9],  l2.y, r0b);
        r0c = fmaf(Ur[0][10], l2.z, r0c); r0d = fmaf(Ur[0][11], l2.w, r0d);
        r1a = fmaf(Ur[1][8],  l2.x, r1a); r1b = fmaf(Ur[1][9],  l2.y, r1b);
        r1c = fmaf(Ur[1][10], l2.z, r1c); r1d = fmaf(Ur[1][11], l2.w, r1d);
        r0a = fmaf(Ur[0][12], l3.x, r0a); r0b = fmaf(Ur[0][13], l3.y, r0b);
        r0c = fmaf(Ur[0][14], l3.z, r0c); r0d = fmaf(Ur[0][15], l3.w, r0d);
        r1a = fmaf(Ur[1][12], l3.x, r1a); r1b = fmaf(Ur[1][13], l3.y, r1b);
        r1c = fmaf(Ur[1][14], l3.z, r1c); r1d = fmaf(Ur[1][15], l3.w, r1d);
        float rec0 = (r0a + r0b) + (r0c + r0d);
        float rec1 = (r1a + r1b) + (r1c + r1d);

        h.x = fmaf(A_COEF, (rec0 + inp0) - h.x, h.x);   // (1-a)h + a(rec+inp)
        h.y = fmaf(A_COEF, (rec1 + inp1) - h.y, h.y);
        ((float2*)(hb + (size_t)t * NN))[p] = h;        // coalesced b64, fire-and-forget
    }
}

// ---------------------------------------------------------------------------
// Out-projection post-pass: out[b,t,o] = sum_n Out_w[o,n] * tanh(hidden[b,t,n])
// One wave per (b,t) row, grid-stride. Memory-bound (~128 MB read, largely
// L3-resident); runs on all 256 CUs, off the scan's critical path.
// ---------------------------------------------------------------------------
__global__ __launch_bounds__(256) void out_kernel(
    const float* __restrict__ hidden,  // [B,T,N]
    const float* __restrict__ Out_w,   // [OUTC,N]
    float* __restrict__ out)           // [B,T,OUTC]
{
    const int wv = (blockIdx.x << 2) | (threadIdx.x >> 6);  // global wave id
    const int p  = threadIdx.x & 63;                        // lane in wave
    const int NW = gridDim.x << 2;

    // Ow regs: lane p covers n in {p*4..p*4+3} and {256+p*4..256+p*4+3}
    float Ow[OUTC][8];
    #pragma unroll
    for (int o = 0; o < OUTC; ++o) {
        float4 w0 = *(const float4*)&Out_w[o * NN + p * 4];
        float4 w1 = *(const float4*)&Out_w[o * NN + 256 + p * 4];
        Ow[o][0] = w0.x; Ow[o][1] = w0.y; Ow[o][2] = w0.z; Ow[o][3] = w0.w;
        Ow[o][4] = w1.x; Ow[o][5] = w1.y; Ow[o][6] = w1.z; Ow[o][7] = w1.w;
    }

    const int ROWS = BATCH * TT;
    for (int r = wv; r < ROWS; r += NW) {
        const float4* hp = (const float4*)(hidden + (size_t)r * NN);
        float4 a = hp[p];        // n = p*4 .. p*4+3       (coalesced 1 KB/wave)
        float4 c = hp[64 + p];   // n = 256+p*4 .. +3      (coalesced 1 KB/wave)
        float ph[8];
        ph[0] = fast_tanh(a.x); ph[1] = fast_tanh(a.y);
        ph[2] = fast_tanh(a.z); ph[3] = fast_tanh(a.w);
        ph[4] = fast_tanh(c.x); ph[5] = fast_tanh(c.y);
        ph[6] = fast_tanh(c.z); ph[7] = fast_tanh(c.w);
        #pragma unroll
        for (int o = 0; o < OUTC; ++o) {
            float sa = Ow[o][0] * ph[0];
            float sb = Ow[o][1] * ph[1];
            sa = fmaf(Ow[o][2], ph[2], sa);
            sb = fmaf(Ow[o][3], ph[3], sb);
            sa = fmaf(Ow[o][4], ph[4], sa);
            sb = fmaf(Ow[o][5], ph[5], sb);
            sa = fmaf(Ow[o][6], ph[6], sa);
            sb = fmaf(Ow[o][7], ph[7], sb);
            float s = sa + sb;
            s = wave_sum(s);                      // DPP, result in lane 63
            if (p == 63) out[(size_t)r * OUTC + o] = s;
        }
    }
}

extern "C" void kernel_launch(void* const* d_in, const int* in_sizes, int n_in,
                              void* d_out, int out_size, void* d_ws, size_t ws_size,
                              hipStream_t stream) {
    const float* x    = (const float*)d_in[0];  // [64,1024,16]
    const float* In_w = (const float*)d_in[1];  // [512,16]
    const float* V_w  = (const float*)d_in[2];  // [16,512]
    const float* U_w  = (const float*)d_in[3];  // [512,16]
    const float* Ow   = (const float*)d_in[4];  // [8,512]
    const float* h0   = (const float*)d_in[5];  // [512]

    float* hidden = (float*)d_out;                         // [64,1024,512]
    float* out    = hidden + (size_t)BATCH * TT * NN;      // [64,1024,8]

    // 64 blocks x 256 threads: one batch per block, 4 waves to barrier.
    scan_kernel<<<BATCH, 256, 0, stream>>>(x, In_w, V_w, U_w, h0, hidden);
    // Out-projection from stored hidden: 1024 blocks x 256 thr = 4096 waves.
    out_kernel<<<1024, 256, 0, stream>>>(hidden, Ow, out);
}